// Round 1
// baseline (1626.612 us; speedup 1.0000x reference)
//
#include <hip/hip_runtime.h>

typedef short  s16x8 __attribute__((ext_vector_type(8)));
typedef __bf16 bf16x8 __attribute__((ext_vector_type(8)));
typedef float  f32x4 __attribute__((ext_vector_type(4)));

#define AS1(p) ((const __attribute__((address_space(1))) void*)(p))
#define AS3(p) ((__attribute__((address_space(3))) void*)(p))

// ---------- f32 -> bf16 cast (vectorized: 8 elems / thread-iter) ----------
__global__ void cast_f32_bf16(const float* __restrict__ in, __bf16* __restrict__ out, int n8){
  int stride = gridDim.x * blockDim.x;
  for (int i = blockIdx.x * blockDim.x + threadIdx.x; i < n8; i += stride){
    const float4* p = (const float4*)in + 2*(size_t)i;
    float4 a = p[0], b = p[1];
    bf16x8 o;
    o[0]=(__bf16)a.x; o[1]=(__bf16)a.y; o[2]=(__bf16)a.z; o[3]=(__bf16)a.w;
    o[4]=(__bf16)b.x; o[5]=(__bf16)b.y; o[6]=(__bf16)b.z; o[7]=(__bf16)b.w;
    ((bf16x8*)out)[i] = o;
  }
}

// ---------- CSR build ----------
__global__ void hist_rows(const int* __restrict__ rows, int* __restrict__ counts, int n){
  int stride = gridDim.x * blockDim.x;
  for (int i = blockIdx.x * blockDim.x + threadIdx.x; i < n; i += stride)
    atomicAdd(&counts[rows[i]], 1);
}

__global__ __launch_bounds__(1024) void scan_rows(const int* __restrict__ counts,
    int* __restrict__ row_ptr, int* __restrict__ cursor, int n){
  __shared__ int sb[1024];
  int t = threadIdx.x;
  int L = (n + 1023) / 1024;
  int lo = t * L, hi = lo + L; if (hi > n) hi = n; if (lo > n) lo = n;
  int sum = 0;
  for (int i = lo; i < hi; i++) sum += counts[i];
  sb[t] = sum;
  __syncthreads();
  for (int d = 1; d < 1024; d <<= 1){
    int v = (t >= d) ? sb[t - d] : 0;
    __syncthreads();
    sb[t] += v;
    __syncthreads();
  }
  int run = sb[t] - sum;  // exclusive prefix
  for (int i = lo; i < hi; i++){
    row_ptr[i] = run; cursor[i] = run; run += counts[i];
  }
  if (t == 1023) row_ptr[n] = sb[1023];
}

__global__ void scatter_edges(const int* __restrict__ rows, const int* __restrict__ cols,
    const float* __restrict__ vals, int* __restrict__ cursor,
    int* __restrict__ ocol, float* __restrict__ oval, int n){
  int stride = gridDim.x * blockDim.x;
  for (int i = blockIdx.x * blockDim.x + threadIdx.x; i < n; i += stride){
    int r = rows[i];
    int p = atomicAdd(&cursor[r], 1);
    ocol[p] = cols[i];
    oval[p] = vals[i];
  }
}

// ---------- SpMM gather: one wave per destination row, f32 accum, ReLU, bf16 out ----------
__global__ __launch_bounds__(256) void spmm_relu(
    const int* __restrict__ rp, const int* __restrict__ cols, const float* __restrict__ vals,
    const __bf16* __restrict__ H, __bf16* __restrict__ O, int n){
  int w = (blockIdx.x * 256 + threadIdx.x) >> 6;
  int lane = threadIdx.x & 63;
  if (w >= n) return;
  int s = rp[w], e = rp[w + 1];
  float acc[8] = {0,0,0,0,0,0,0,0};
  for (int i = s; i < e; i++){
    int c = cols[i];
    float v = vals[i];
    s16x8 hv = *(const s16x8*)(H + (size_t)c * 512 + lane * 8);
    #pragma unroll
    for (int k = 0; k < 8; k++){
      unsigned u = ((unsigned)(unsigned short)hv[k]) << 16;
      acc[k] = fmaf(v, __builtin_bit_cast(float, u), acc[k]);
    }
  }
  s16x8 o;
  #pragma unroll
  for (int k = 0; k < 8; k++){
    float v = fmaxf(acc[k], 0.f);
    o[k] = __builtin_bit_cast(short, (__bf16)v);
  }
  *(s16x8*)(O + (size_t)w * 512 + lane * 8) = o;
}

// ---------- bf16 MFMA GEMM, C[m][n] = sum_k A[m][k]*B[n][k] (B^T layout) ----------
// m97 structure: 128x128 tile, BK=64, 4 waves (2x2), global_load_lds width 16.
template<int RELU, int OUT_BF16>
__global__ __launch_bounds__(256) void gemm_bt(
    const __bf16* __restrict__ A, const __bf16* __restrict__ B,
    void* __restrict__ C, int M, int N, int K){
  __shared__ __attribute__((aligned(16))) __bf16 As[128 * 64];
  __shared__ __attribute__((aligned(16))) __bf16 Bs[128 * 64];
  const int ntiles = N >> 7;
  const int tm = blockIdx.x / ntiles;
  const int tn = blockIdx.x % ntiles;
  const int row0 = tm << 7, col0 = tn << 7;
  const int tid = threadIdx.x;
  const int lane = tid & 63, wid = tid >> 6;
  const int wm = (wid >> 1) * 64, wn = (wid & 1) * 64;
  const int lr = lane & 15;
  const int lkb = ((lane >> 4) * 8) * 2;   // k-offset in bytes within BK row

  f32x4 acc[4][4] = {};

  for (int k0 = 0; k0 < K; k0 += 64){
    __syncthreads();
    #pragma unroll
    for (int i = 0; i < 4; i++){
      int bo = tid * 16 + i * 4096;   // byte offset in 128x128B tile
      int r  = bo >> 7;               // row
      int cb = bo & 127;              // byte within row
      int ga = row0 + r; ga = ga < M ? ga : M - 1;
      __builtin_amdgcn_global_load_lds(AS1(A + (size_t)ga * K + k0 + (cb >> 1)),
                                       AS3((char*)As + (wid << 10) + i * 4096), 16, 0, 0);
      int gb = col0 + r;
      __builtin_amdgcn_global_load_lds(AS1(B + (size_t)gb * K + k0 + (cb >> 1)),
                                       AS3((char*)Bs + (wid << 10) + i * 4096), 16, 0, 0);
    }
    __syncthreads();
    #pragma unroll
    for (int kk = 0; kk < 2; kk++){
      s16x8 af[4], bfr[4];
      #pragma unroll
      for (int i = 0; i < 4; i++)
        af[i] = *(const s16x8*)((const char*)As + (wm + i * 16 + lr) * 128 + kk * 64 + lkb);
      #pragma unroll
      for (int j = 0; j < 4; j++)
        bfr[j] = *(const s16x8*)((const char*)Bs + (wn + j * 16 + lr) * 128 + kk * 64 + lkb);
      #pragma unroll
      for (int i = 0; i < 4; i++)
        #pragma unroll
        for (int j = 0; j < 4; j++)
          acc[i][j] = __builtin_amdgcn_mfma_f32_16x16x32_bf16(af[i], bfr[j], acc[i][j], 0, 0, 0);
    }
  }

  const int orow = (lane >> 4) * 4;
  #pragma unroll
  for (int i = 0; i < 4; i++){
    #pragma unroll
    for (int j = 0; j < 4; j++){
      int gc = col0 + wn + j * 16 + lr;
      #pragma unroll
      for (int r = 0; r < 4; r++){
        int gr = row0 + wm + i * 16 + orow + r;
        if (gr < M){
          float v = acc[i][j][r];
          if (RELU) v = fmaxf(v, 0.f);
          if (OUT_BF16) ((__bf16*)C)[(size_t)gr * N + gc] = (__bf16)v;
          else          ((float*)C)[(size_t)gr * N + gc] = v;
        }
      }
    }
  }
}

extern "C" void kernel_launch(void* const* d_in, const int* in_sizes, int n_in,
                              void* d_out, int out_size, void* d_ws, size_t ws_size,
                              hipStream_t stream){
  const float* x    = (const float*)d_in[0];
  const int*   erow = (const int*)d_in[1];
  const int*   ecol = (const int*)d_in[2];
  const float* eval = (const float*)d_in[3];
  const float* W0   = (const float*)d_in[4];
  const float* W1   = (const float*)d_in[5];
  const float* W2   = (const float*)d_in[6];

  const int DIN = 512, DH = 512, DO = 256;
  const int NN = in_sizes[0] / DIN;   // 100000
  const int NE = in_sizes[1];         // 3200000

  size_t off = 0;
  auto carve = [&](size_t b) -> char* {
    char* p = (char*)d_ws + off; off += (b + 255) & ~(size_t)255; return p;
  };
  __bf16* bufA  = (__bf16*)carve((size_t)NN * DIN * 2); // x_bf16, later h1
  __bf16* bufB  = (__bf16*)carve((size_t)NN * DH * 2);  // h0, later h2
  __bf16* wW0   = (__bf16*)carve((size_t)DH * DIN * 2);
  __bf16* wW1   = (__bf16*)carve((size_t)DH * DH * 2);
  __bf16* wW2   = (__bf16*)carve((size_t)DO * DH * 2);
  int*   counts = (int*)carve((size_t)NN * 4);
  int*   rp     = (int*)carve(((size_t)NN + 1) * 4);
  int*   cursor = (int*)carve((size_t)NN * 4);
  int*   cs     = (int*)carve((size_t)NE * 4);
  float* vs     = (float*)carve((size_t)NE * 4);

  hipMemsetAsync(counts, 0, (size_t)NN * 4, stream);

  cast_f32_bf16<<<4096, 256, 0, stream>>>(x,  bufA, NN * DIN / 8);
  cast_f32_bf16<<<256,  256, 0, stream>>>(W0, wW0, DH * DIN / 8);
  cast_f32_bf16<<<256,  256, 0, stream>>>(W1, wW1, DH * DH / 8);
  cast_f32_bf16<<<128,  256, 0, stream>>>(W2, wW2, DO * DH / 8);

  hist_rows<<<2048, 256, 0, stream>>>(erow, counts, NE);
  scan_rows<<<1, 1024, 0, stream>>>(counts, rp, cursor, NN);
  scatter_edges<<<2048, 256, 0, stream>>>(erow, ecol, eval, cursor, cs, vs, NE);

  const int mt = (NN + 127) / 128;
  gemm_bt<0,1><<<dim3(mt * (DH / 128)), 256, 0, stream>>>(bufA, wW0, bufB, NN, DH, DIN);
  spmm_relu<<<(NN * 64 + 255) / 256, 256, 0, stream>>>(rp, cs, vs, bufB, bufA, NN);
  gemm_bt<1,1><<<dim3(mt * (DH / 128)), 256, 0, stream>>>(bufA, wW1, bufB, NN, DH, DH);
  gemm_bt<0,0><<<dim3(mt * (DO / 128)), 256, 0, stream>>>(bufB, wW2, d_out, NN, DO, DH);
}

// Round 2
// 1449.740 us; speedup vs baseline: 1.1220x; 1.1220x over previous
//
#include <hip/hip_runtime.h>

typedef short  s16x8 __attribute__((ext_vector_type(8)));
typedef __bf16 bf16x8 __attribute__((ext_vector_type(8)));
typedef float  f32x4 __attribute__((ext_vector_type(4)));

#define AS1(p) ((const __attribute__((address_space(1))) void*)(p))
#define AS3(p) ((__attribute__((address_space(3))) void*)(p))

__device__ __forceinline__ float bf2f(short x){
  unsigned u = ((unsigned)(unsigned short)x) << 16;
  return __builtin_bit_cast(float, u);
}

// ---------- f32 -> bf16 cast (vectorized: 8 elems / thread-iter) ----------
__global__ void cast_f32_bf16(const float* __restrict__ in, __bf16* __restrict__ out, int n8){
  int stride = gridDim.x * blockDim.x;
  for (int i = blockIdx.x * blockDim.x + threadIdx.x; i < n8; i += stride){
    const float4* p = (const float4*)in + 2*(size_t)i;
    float4 a = p[0], b = p[1];
    bf16x8 o;
    o[0]=(__bf16)a.x; o[1]=(__bf16)a.y; o[2]=(__bf16)a.z; o[3]=(__bf16)a.w;
    o[4]=(__bf16)b.x; o[5]=(__bf16)b.y; o[6]=(__bf16)b.z; o[7]=(__bf16)b.w;
    ((bf16x8*)out)[i] = o;
  }
}

// ---------- CSR build ----------
__global__ void hist_rows(const int* __restrict__ rows, int* __restrict__ counts, int n){
  int stride = gridDim.x * blockDim.x;
  for (int i = blockIdx.x * blockDim.x + threadIdx.x; i < n; i += stride)
    atomicAdd(&counts[rows[i]], 1);
}

// 3-phase coalesced exclusive scan of counts[n] -> rp[n] (+rp[n]=NE), cursor copy.
__global__ __launch_bounds__(256) void scan_phaseA(const int* __restrict__ counts,
    int* __restrict__ rp, int* __restrict__ bsum, int n4){
  __shared__ int sb[256];
  int t = threadIdx.x;
  int idx = blockIdx.x * 256 + t;       // int4 index
  int4 c = make_int4(0,0,0,0);
  if (idx < n4) c = ((const int4*)counts)[idx];
  int s = c.x + c.y + c.z + c.w;
  sb[t] = s; __syncthreads();
  #pragma unroll
  for (int d = 1; d < 256; d <<= 1){
    int v = (t >= d) ? sb[t - d] : 0;
    __syncthreads();
    sb[t] += v;
    __syncthreads();
  }
  int ex = sb[t] - s;                   // exclusive within block
  if (idx < n4){
    int4 o; o.x = ex; o.y = ex + c.x; o.z = o.y + c.y; o.w = o.z + c.z;
    ((int4*)rp)[idx] = o;
  }
  if (t == 255) bsum[blockIdx.x] = sb[255];
}

__global__ __launch_bounds__(128) void scan_phaseB(int* __restrict__ bsum, int nb){
  __shared__ int sb[128];
  int t = threadIdx.x;
  int v = (t < nb) ? bsum[t] : 0;
  sb[t] = v; __syncthreads();
  #pragma unroll
  for (int d = 1; d < 128; d <<= 1){
    int u = (t >= d) ? sb[t - d] : 0;
    __syncthreads();
    sb[t] += u;
    __syncthreads();
  }
  if (t < nb) bsum[t] = sb[t] - v;      // exclusive block offsets
}

__global__ void scan_phaseC(const int* __restrict__ bsum, int* __restrict__ rp,
    int* __restrict__ cursor, int n, int ne){
  int i = blockIdx.x * 256 + threadIdx.x;
  if (i < n){
    int v = rp[i] + bsum[i >> 10];      // 1024 elements per phaseA block
    rp[i] = v; cursor[i] = v;
  }
  if (i == 0) rp[n] = ne;
}

__global__ void scatter_edges(const int* __restrict__ rows, const int* __restrict__ cols,
    const float* __restrict__ vals, int* __restrict__ cursor,
    int2* __restrict__ ev, int n){
  int stride = gridDim.x * blockDim.x;
  for (int i = blockIdx.x * blockDim.x + threadIdx.x; i < n; i += stride){
    int r = rows[i];
    int p = atomicAdd(&cursor[r], 1);
    ev[p] = make_int2(cols[i], __float_as_int(vals[i]));
  }
}

// ---------- SpMM gather: one wave per destination row, 4 gathers in flight ----------
__global__ __launch_bounds__(256) void spmm_relu(
    const int* __restrict__ rp, const int2* __restrict__ ev,
    const __bf16* __restrict__ H, __bf16* __restrict__ O, int n){
  int w = (blockIdx.x * 256 + threadIdx.x) >> 6;
  int lane = threadIdx.x & 63;
  if (w >= n) return;
  int s = rp[w], e = rp[w + 1];
  int deg = e - s;
  const __bf16* Hl = H + lane * 8;
  float acc[8] = {0,0,0,0,0,0,0,0};

  // cooperative coalesced load of up to 64 (col,val) pairs; broadcast via readlane
  int2 cv = make_int2(0, 0);
  if (lane < deg) cv = ev[s + lane];
  int m = deg < 64 ? deg : 64;
  int i = 0;
  for (; i + 4 <= m; i += 4){
    int c0 = __builtin_amdgcn_readlane(cv.x, i);
    int c1 = __builtin_amdgcn_readlane(cv.x, i + 1);
    int c2 = __builtin_amdgcn_readlane(cv.x, i + 2);
    int c3 = __builtin_amdgcn_readlane(cv.x, i + 3);
    float v0 = __builtin_bit_cast(float, __builtin_amdgcn_readlane(cv.y, i));
    float v1 = __builtin_bit_cast(float, __builtin_amdgcn_readlane(cv.y, i + 1));
    float v2 = __builtin_bit_cast(float, __builtin_amdgcn_readlane(cv.y, i + 2));
    float v3 = __builtin_bit_cast(float, __builtin_amdgcn_readlane(cv.y, i + 3));
    s16x8 h0 = *(const s16x8*)(Hl + (size_t)c0 * 512);
    s16x8 h1 = *(const s16x8*)(Hl + (size_t)c1 * 512);
    s16x8 h2 = *(const s16x8*)(Hl + (size_t)c2 * 512);
    s16x8 h3 = *(const s16x8*)(Hl + (size_t)c3 * 512);
    #pragma unroll
    for (int k = 0; k < 8; k++){
      acc[k] = fmaf(v0, bf2f(h0[k]), acc[k]);
      acc[k] = fmaf(v1, bf2f(h1[k]), acc[k]);
      acc[k] = fmaf(v2, bf2f(h2[k]), acc[k]);
      acc[k] = fmaf(v3, bf2f(h3[k]), acc[k]);
    }
  }
  for (; i < m; i++){
    int c = __builtin_amdgcn_readlane(cv.x, i);
    float v = __builtin_bit_cast(float, __builtin_amdgcn_readlane(cv.y, i));
    s16x8 h0 = *(const s16x8*)(Hl + (size_t)c * 512);
    #pragma unroll
    for (int k = 0; k < 8; k++) acc[k] = fmaf(v, bf2f(h0[k]), acc[k]);
  }
  for (int j = s + 64; j < e; j++){   // rare tail: deg > 64
    int2 p = ev[j];
    float v = __builtin_bit_cast(float, p.y);
    s16x8 h0 = *(const s16x8*)(Hl + (size_t)p.x * 512);
    #pragma unroll
    for (int k = 0; k < 8; k++) acc[k] = fmaf(v, bf2f(h0[k]), acc[k]);
  }

  s16x8 o;
  #pragma unroll
  for (int k = 0; k < 8; k++){
    float v = fmaxf(acc[k], 0.f);
    o[k] = __builtin_bit_cast(short, (__bf16)v);
  }
  *(s16x8*)(O + (size_t)w * 512 + lane * 8) = o;
}

// ---------- bf16 MFMA GEMM, C[m][n] = sum_k A[m][k]*B[n][k] (B^T layout) ----------
template<int RELU, int OUT_BF16>
__global__ __launch_bounds__(256) void gemm_bt(
    const __bf16* __restrict__ A, const __bf16* __restrict__ B,
    void* __restrict__ C, int M, int N, int K){
  __shared__ __attribute__((aligned(16))) __bf16 As[128 * 64];
  __shared__ __attribute__((aligned(16))) __bf16 Bs[128 * 64];
  const int ntiles = N >> 7;
  const int tm = blockIdx.x / ntiles;
  const int tn = blockIdx.x % ntiles;
  const int row0 = tm << 7, col0 = tn << 7;
  const int tid = threadIdx.x;
  const int lane = tid & 63, wid = tid >> 6;
  const int wm = (wid >> 1) * 64, wn = (wid & 1) * 64;
  const int lr = lane & 15;
  const int lkb = ((lane >> 4) * 8) * 2;

  f32x4 acc[4][4] = {};

  for (int k0 = 0; k0 < K; k0 += 64){
    __syncthreads();
    #pragma unroll
    for (int i = 0; i < 4; i++){
      int bo = tid * 16 + i * 4096;
      int r  = bo >> 7;
      int cb = bo & 127;
      int ga = row0 + r; ga = ga < M ? ga : M - 1;
      __builtin_amdgcn_global_load_lds(AS1(A + (size_t)ga * K + k0 + (cb >> 1)),
                                       AS3((char*)As + (wid << 10) + i * 4096), 16, 0, 0);
      int gb = col0 + r;
      __builtin_amdgcn_global_load_lds(AS1(B + (size_t)gb * K + k0 + (cb >> 1)),
                                       AS3((char*)Bs + (wid << 10) + i * 4096), 16, 0, 0);
    }
    __syncthreads();
    #pragma unroll
    for (int kk = 0; kk < 2; kk++){
      s16x8 af[4], bfr[4];
      #pragma unroll
      for (int i = 0; i < 4; i++)
        af[i] = *(const s16x8*)((const char*)As + (wm + i * 16 + lr) * 128 + kk * 64 + lkb);
      #pragma unroll
      for (int j = 0; j < 4; j++)
        bfr[j] = *(const s16x8*)((const char*)Bs + (wn + j * 16 + lr) * 128 + kk * 64 + lkb);
      #pragma unroll
      for (int i = 0; i < 4; i++)
        #pragma unroll
        for (int j = 0; j < 4; j++)
          acc[i][j] = __builtin_amdgcn_mfma_f32_16x16x32_bf16(af[i], bfr[j], acc[i][j], 0, 0, 0);
    }
  }

  const int orow = (lane >> 4) * 4;
  #pragma unroll
  for (int i = 0; i < 4; i++){
    #pragma unroll
    for (int j = 0; j < 4; j++){
      int gc = col0 + wn + j * 16 + lr;
      #pragma unroll
      for (int r = 0; r < 4; r++){
        int gr = row0 + wm + i * 16 + orow + r;
        if (gr < M){
          float v = acc[i][j][r];
          if (RELU) v = fmaxf(v, 0.f);
          if (OUT_BF16) ((__bf16*)C)[(size_t)gr * N + gc] = (__bf16)v;
          else          ((float*)C)[(size_t)gr * N + gc] = v;
        }
      }
    }
  }
}

extern "C" void kernel_launch(void* const* d_in, const int* in_sizes, int n_in,
                              void* d_out, int out_size, void* d_ws, size_t ws_size,
                              hipStream_t stream){
  const float* x    = (const float*)d_in[0];
  const int*   erow = (const int*)d_in[1];
  const int*   ecol = (const int*)d_in[2];
  const float* eval = (const float*)d_in[3];
  const float* W0   = (const float*)d_in[4];
  const float* W1   = (const float*)d_in[5];
  const float* W2   = (const float*)d_in[6];

  const int DIN = 512, DH = 512, DO = 256;
  const int NN = in_sizes[0] / DIN;   // 100000
  const int NE = in_sizes[1];         // 3200000

  size_t off = 0;
  auto carve = [&](size_t b) -> char* {
    char* p = (char*)d_ws + off; off += (b + 255) & ~(size_t)255; return p;
  };
  __bf16* bufA  = (__bf16*)carve((size_t)NN * DIN * 2); // x_bf16, later h1
  __bf16* bufB  = (__bf16*)carve((size_t)NN * DH * 2);  // h0, later h2
  __bf16* wW0   = (__bf16*)carve((size_t)DH * DIN * 2);
  __bf16* wW1   = (__bf16*)carve((size_t)DH * DH * 2);
  __bf16* wW2   = (__bf16*)carve((size_t)DO * DH * 2);
  int*   counts = (int*)carve((size_t)NN * 4);
  int*   rp     = (int*)carve(((size_t)NN + 1) * 4);
  int*   cursor = (int*)carve((size_t)NN * 4);
  int*   bsum   = (int*)carve(4096);
  int2*  ev     = (int2*)carve((size_t)NE * 8);

  hipMemsetAsync(counts, 0, (size_t)NN * 4, stream);

  cast_f32_bf16<<<4096, 256, 0, stream>>>(x,  bufA, NN * DIN / 8);
  cast_f32_bf16<<<256,  256, 0, stream>>>(W0, wW0, DH * DIN / 8);
  cast_f32_bf16<<<256,  256, 0, stream>>>(W1, wW1, DH * DH / 8);
  cast_f32_bf16<<<128,  256, 0, stream>>>(W2, wW2, DO * DH / 8);

  hist_rows<<<2048, 256, 0, stream>>>(erow, counts, NE);
  const int n4 = NN / 4;                       // 25000 int4s
  const int nblkA = (n4 + 255) / 256;          // 98
  scan_phaseA<<<nblkA, 256, 0, stream>>>(counts, rp, bsum, n4);
  scan_phaseB<<<1, 128, 0, stream>>>(bsum, nblkA);
  scan_phaseC<<<(NN + 255) / 256, 256, 0, stream>>>(bsum, rp, cursor, NN, NE);
  scatter_edges<<<2048, 256, 0, stream>>>(erow, ecol, eval, cursor, ev, NE);

  const int mt = (NN + 127) / 128;
  gemm_bt<0,1><<<dim3(mt * (DH / 128)), 256, 0, stream>>>(bufA, wW0, bufB, NN, DH, DIN);
  spmm_relu<<<(NN * 64 + 255) / 256, 256, 0, stream>>>(rp, ev, bufB, bufA, NN);
  gemm_bt<1,1><<<dim3(mt * (DH / 128)), 256, 0, stream>>>(bufA, wW1, bufB, NN, DH, DH);
  gemm_bt<0,0><<<dim3(mt * (DO / 128)), 256, 0, stream>>>(bufB, wW2, d_out, NN, DO, DH);
}